// Round 16
// baseline (96.986 us; speedup 1.0000x reference)
//
#include <hip/hip_runtime.h>

typedef __bf16 bf16x8 __attribute__((ext_vector_type(8)));
typedef short  s16x8  __attribute__((ext_vector_type(8)));
typedef float  f32x4  __attribute__((ext_vector_type(4)));
typedef float  f32x16 __attribute__((ext_vector_type(16)));
typedef unsigned int   u32x4 __attribute__((ext_vector_type(4)));
typedef unsigned short u16x4 __attribute__((ext_vector_type(4)));

#define NH   16
#define HD   64
#define SEQ  1024
#define DM   1024
#define NB   4
#define MTOT 4096   // NB*SEQ

// 0.125 (1/sqrt(dk)) * log2(e): folded into Wq so QK^T scores are in log2 domain
#define SCALE_L2E 0.1803368801111204f

__device__ __forceinline__ unsigned short f2bf(float f) {
    unsigned u = __builtin_bit_cast(unsigned, f);
    u += 0x7FFFu + ((u >> 16) & 1u);          // round-to-nearest-even
    return (unsigned short)(u >> 16);
}

__device__ __forceinline__ s16x8 cvt8(f32x4 a, f32x4 b) {
    s16x8 r;
    r[0] = (short)f2bf(a[0]); r[1] = (short)f2bf(a[1]);
    r[2] = (short)f2bf(a[2]); r[3] = (short)f2bf(a[3]);
    r[4] = (short)f2bf(b[0]); r[5] = (short)f2bf(b[1]);
    r[6] = (short)f2bf(b[2]); r[7] = (short)f2bf(b[3]);
    return r;
}

__device__ __forceinline__ unsigned short bfbits(float x) {
    __bf16 h = (__bf16)x;
    return __builtin_bit_cast(unsigned short, h);
}
__device__ __forceinline__ float bf2f(unsigned short b) {
    unsigned u = (unsigned)b << 16;
    return __builtin_bit_cast(float, u);
}
__device__ __forceinline__ unsigned pk2(float a, float b) {
    return (unsigned)bfbits(a) | ((unsigned)bfbits(b) << 16);
}

__device__ __forceinline__ void gl16(const void* g, void* l) {
    __builtin_amdgcn_global_load_lds(
        (const __attribute__((address_space(1))) unsigned int*)g,
        (__attribute__((address_space(3))) unsigned int*)l, 16, 0, 0);
}

__device__ __forceinline__ bf16x8 ldfrag(const char* base, int row, int cb) {
    return __builtin_bit_cast(bf16x8,
        *(const s16x8*)(base + row * 128 + (cb ^ ((row & 7) << 4))));
}

// ---------------- fp32 -> bf16 convert pass (all 7 tensors) -----------------
__global__ __launch_bounds__(256)
void cvt_kernel(const float* __restrict__ q, const float* __restrict__ k,
                const float* __restrict__ v, const float* __restrict__ wq,
                const float* __restrict__ wk, const float* __restrict__ wv,
                const float* __restrict__ wo,
                unsigned short* __restrict__ dq, unsigned short* __restrict__ dk,
                unsigned short* __restrict__ dv, unsigned short* __restrict__ dwq,
                unsigned short* __restrict__ dwk, unsigned short* __restrict__ dwv,
                unsigned short* __restrict__ dwo)
{
    const int id = blockIdx.x;
    const float* s; unsigned short* d; int off; float scl = 1.0f;
    if (id < 6144) {                       // q,k,v: 2048 blocks each
        const int t = id >> 11; off = id & 2047;
        s = (t == 0) ? q : (t == 1) ? k : v;
        d = (t == 0) ? dq : (t == 1) ? dk : dv;
    } else {                               // weights: 512 blocks each
        const int w = (id - 6144) >> 9; off = (id - 6144) & 511;
        s = (w == 0) ? wq : (w == 1) ? wk : (w == 2) ? wv : wo;
        d = (w == 0) ? dwq : (w == 1) ? dwk : (w == 2) ? dwv : dwo;
        if (w == 0) scl = SCALE_L2E;
    }
    const int idx = off * 2048 + threadIdx.x * 8;
    const f32x4* sp = (const f32x4*)(s + idx);
    *(s16x8*)(d + idx) = cvt8(sp[0] * scl, sp[1] * scl);
}

// ---------------- staging helpers -------------------------------------------
// stage a 128-row x 64-col half-tile (16 KB) with 512 threads (2 gl16/thread)
__device__ __forceinline__ void stage_half(const unsigned short* __restrict__ src,
                                           int grow0, int k0, char* ldsdst, int tid)
{
    const int wv  = tid >> 6;                                // 0..7
    const int row = tid >> 3;                                // 0..63
    const int scx = ((tid & 7) * 16) ^ ((row & 7) << 4);
    gl16((const char*)(src + (size_t)(grow0 + row) * DM + k0) + scx,
         ldsdst + wv * 1024);
    gl16((const char*)(src + (size_t)(grow0 + 64 + row) * DM + k0) + scx,
         ldsdst + 8192 + wv * 1024);
}

// ---------------- QKV projection: 256x256 tile, 8-wave, 4-phase, gl16 -------
// V output layout is FRAGMENT-LINEAR: Vf[bh][t=s64-tile][r=(slot,dhalf)][lane]
__global__ __launch_bounds__(512, 2)
void proj_kernel(const unsigned short* __restrict__ Xq,
                 const unsigned short* __restrict__ Xk,
                 const unsigned short* __restrict__ Xv,
                 const unsigned short* __restrict__ Wq,
                 const unsigned short* __restrict__ Wk,
                 const unsigned short* __restrict__ Wv,
                 unsigned short* __restrict__ Qo, unsigned short* __restrict__ Ko,
                 unsigned short* __restrict__ VTo)
{
    __shared__ char smem[147456];

    const int bid = blockIdx.x;
    const int swz = (bid & 7) * 24 + (bid >> 3);
    const int which = swz >> 6;                 // 0..2
    const int rem   = swz & 63;
    const int m0 = (rem >> 2) * 256, n0 = (rem & 3) * 256;

    const unsigned short* X = (which == 0) ? Xq : (which == 1) ? Xk : Xv;
    const unsigned short* W = (which == 0) ? Wq : (which == 1) ? Wk : Wv;

    const int tid = threadIdx.x, lane = tid & 63, wv = tid >> 6;
    const int wrB = (wv >> 2) * 128;
    const int wcB = (wv & 3) * 64;
    const int fr = lane & 15, hi = lane >> 4, r4 = hi * 4;

    f32x4 acc[8][4];
    #pragma unroll
    for (int i = 0; i < 8; ++i)
        #pragma unroll
        for (int j = 0; j < 4; ++j) acc[i][j] = (f32x4){0.f, 0.f, 0.f, 0.f};

    stage_half(X, m0,       0, smem +     0, tid);
    stage_half(X, m0 + 128, 0, smem + 16384, tid);
    stage_half(W, n0,       0, smem + 32768, tid);
    stage_half(W, n0 + 128, 0, smem + 49152, tid);

    for (int t = 0; t < 16; ++t) {
        const char* Abuf = smem + (t & 1) * 65536;
        const char* Bbuf = Abuf + 32768;
        char* nb = smem + ((t & 1) ^ 1) * 65536;
        const int kn = (t + 1) * 64;

        bf16x8 af[2][4], bf01[2][2], bf23[2][2];

        // ---- phase 0: stage A-h0(t+1); counted vmcnt; barrier; af(qm0)+bf01; MFMA
        if (t < 15) {
            stage_half(X, m0, kn, nb, tid);
            asm volatile("s_waitcnt vmcnt(2)" ::: "memory");   // tile t fully landed
        } else {
            asm volatile("s_waitcnt vmcnt(0)" ::: "memory");
        }
        __builtin_amdgcn_s_barrier();
        __builtin_amdgcn_sched_barrier(0);
        #pragma unroll
        for (int ks = 0; ks < 2; ++ks) {
            const int cb = ks * 64 + hi * 16;
            #pragma unroll
            for (int mt = 0; mt < 4; ++mt) af[ks][mt] = ldfrag(Abuf, wrB + mt * 16 + fr, cb);
            #pragma unroll
            for (int nt = 0; nt < 2; ++nt) bf01[ks][nt] = ldfrag(Bbuf, wcB + nt * 16 + fr, cb);
        }
        __builtin_amdgcn_s_setprio(1);
        #pragma unroll
        for (int ks = 0; ks < 2; ++ks)
            #pragma unroll
            for (int mt = 0; mt < 4; ++mt)
                #pragma unroll
                for (int nt = 0; nt < 2; ++nt)
                    acc[mt][nt] = __builtin_amdgcn_mfma_f32_16x16x32_bf16(
                        af[ks][mt], bf01[ks][nt], acc[mt][nt], 0, 0, 0);
        __builtin_amdgcn_s_setprio(0);

        // ---- phase 1: bf23; stage A-h1(t+1); MFMA qm0 x nt{2,3}
        __builtin_amdgcn_s_barrier();
        __builtin_amdgcn_sched_barrier(0);
        #pragma unroll
        for (int ks = 0; ks < 2; ++ks) {
            const int cb = ks * 64 + hi * 16;
            #pragma unroll
            for (int nt = 0; nt < 2; ++nt) bf23[ks][nt] = ldfrag(Bbuf, wcB + 32 + nt * 16 + fr, cb);
        }
        if (t < 15) stage_half(X, m0 + 128, kn, nb + 16384, tid);
        __builtin_amdgcn_s_setprio(1);
        #pragma unroll
        for (int ks = 0; ks < 2; ++ks)
            #pragma unroll
            for (int mt = 0; mt < 4; ++mt)
                #pragma unroll
                for (int nt = 0; nt < 2; ++nt)
                    acc[mt][nt + 2] = __builtin_amdgcn_mfma_f32_16x16x32_bf16(
                        af[ks][mt], bf23[ks][nt], acc[mt][nt + 2], 0, 0, 0);
        __builtin_amdgcn_s_setprio(0);

        // ---- phase 2: af(qm1); stage B-h0(t+1); MFMA qm1 x nt{0,1}
        __builtin_amdgcn_s_barrier();
        __builtin_amdgcn_sched_barrier(0);
        #pragma unroll
        for (int ks = 0; ks < 2; ++ks) {
            const int cb = ks * 64 + hi * 16;
            #pragma unroll
            for (int mt = 0; mt < 4; ++mt) af[ks][mt] = ldfrag(Abuf, wrB + 64 + mt * 16 + fr, cb);
        }
        if (t < 15) stage_half(W, n0, kn, nb + 32768, tid);
        __builtin_amdgcn_s_setprio(1);
        #pragma unroll
        for (int ks = 0; ks < 2; ++ks)
            #pragma unroll
            for (int mt = 0; mt < 4; ++mt)
                #pragma unroll
                for (int nt = 0; nt < 2; ++nt)
                    acc[mt + 4][nt] = __builtin_amdgcn_mfma_f32_16x16x32_bf16(
                        af[ks][mt], bf01[ks][nt], acc[mt + 4][nt], 0, 0, 0);
        __builtin_amdgcn_s_setprio(0);

        // ---- phase 3: stage B-h1(t+1); MFMA qm1 x nt{2,3}
        __builtin_amdgcn_s_barrier();
        __builtin_amdgcn_sched_barrier(0);
        if (t < 15) stage_half(W, n0 + 128, kn, nb + 49152, tid);
        __builtin_amdgcn_s_setprio(1);
        #pragma unroll
        for (int ks = 0; ks < 2; ++ks)
            #pragma unroll
            for (int mt = 0; mt < 4; ++mt)
                #pragma unroll
                for (int nt = 0; nt < 2; ++nt)
                    acc[mt + 4][nt + 2] = __builtin_amdgcn_mfma_f32_16x16x32_bf16(
                        af[ks][mt], bf23[ks][nt], acc[mt + 4][nt + 2], 0, 0, 0);
        __builtin_amdgcn_s_setprio(0);
    }

    // ---------------- vectorized epilogue via per-wave LDS bounce -----------
    __syncthreads();

    unsigned short* sE = (unsigned short*)(smem + wv * 18432);
    #pragma unroll
    for (int mt = 0; mt < 8; ++mt)
        #pragma unroll
        for (int nt = 0; nt < 4; ++nt)
            #pragma unroll
            for (int r = 0; r < 4; ++r) {
                const int row = mt * 16 + r4 + r;
                const int col = nt * 16 + fr;
                sE[row * 72 + (col ^ (((row >> 3) & 7) << 3))] = f2bf(acc[mt][nt][r]);
            }
    asm volatile("s_waitcnt lgkmcnt(0)" ::: "memory");

    const int hB    = (n0 + wcB) >> 6;
    const int sbase = m0 + wrB;
    const int bb    = sbase >> 10;
    const int srow0 = sbase & 1023;

    if (which < 2) {
        unsigned short* QK = ((which == 0) ? Qo : Ko)
            + (((size_t)(bb * NH + hB)) * SEQ + srow0) * HD;
        #pragma unroll
        for (int it = 0; it < 16; ++it) {
            const int idx = it * 64 + lane;
            const int row = idx >> 3, c = idx & 7;
            s16x8 v = *(const s16x8*)&sE[row * 72 + ((c ^ ((row >> 3) & 7)) * 8)];
            *(s16x8*)(QK + (size_t)row * HD + c * 8) = v;
        }
    } else {
        const int t0 = srow0 >> 6;                       // 2 tiles owned
        unsigned short* VD = VTo + (size_t)(bb * NH + hB) * (SEQ * HD)
                                 + (size_t)t0 * 4096;
        #pragma unroll
        for (int it = 0; it < 16; ++it) {
            const int tt = it >> 3, r = it & 7;
            const int sb = tt * 64 + (r >> 1) * 16 + (lane >> 5) * 8;
            const int d  = (lane & 31) + (r & 1) * 32;
            s16x8 v;
            #pragma unroll
            for (int j = 0; j < 8; ++j) {
                const int row = sb + j;
                v[j] = (short)sE[row * 72 + (d ^ (((row >> 3) & 7) << 3))];
            }
            *(s16x8*)(VD + (size_t)(tt * 8 + r) * 512 + lane * 8) = v;  // 1 KB contig
        }
    }
}

// ---------------- output projection: 128^2, 8 waves (2/SIMD), 2-phase -------
__global__ __launch_bounds__(512, 2)
void outproj_kernel(const unsigned short* __restrict__ A,
                    const unsigned short* __restrict__ Wo,
                    const float* __restrict__ bo,
                    float* __restrict__ Cout)
{
    const int bid = blockIdx.x;
    const int swz = (bid & 7) * 32 + (bid >> 3);     // 256 blocks
    const int m0 = (swz >> 3) * 128, n0 = (swz & 7) * 128;

    __shared__ char sA[2][16384];
    __shared__ char sB[2][16384];

    const int tid = threadIdx.x, lane = tid & 63, wv = tid >> 6;
    const int wr = (wv >> 1) * 32;       // 4 M-groups of 32 rows
    const int wc = (wv & 1) * 64;        // 2 N-groups of 64 cols
    const int fr = lane & 15, hi = lane >> 4, r4 = hi * 4;

    f32x4 acc[2][4];
    #pragma unroll
    for (int i = 0; i < 2; ++i)
        #pragma unroll
        for (int j = 0; j < 4; ++j) acc[i][j] = (f32x4){0.f, 0.f, 0.f, 0.f};

    stage_half(A,  m0, 0, sA[0], tid);
    stage_half(Wo, n0, 0, sB[0], tid);

    for (int kt = 0; kt < 16; ++kt) {
        const int cur = kt & 1;
        if (kt < 15) {
            stage_half(A,  m0, (kt + 1) * 64, sA[cur ^ 1], tid);
            stage_half(Wo, n0, (kt + 1) * 64, sB[cur ^ 1], tid);
            asm volatile("s_waitcnt vmcnt(4)" ::: "memory");   // tile kt landed
        } else {
            asm volatile("s_waitcnt vmcnt(0)" ::: "memory");
        }
        __builtin_amdgcn_s_barrier();
        __builtin_amdgcn_sched_barrier(0);
        #pragma unroll
        for (int ks = 0; ks < 2; ++ks) {
            const int cb = ks * 64 + hi * 16;
            bf16x8 af[2], bfm[4];
            #pragma unroll
            for (int mt = 0; mt < 2; ++mt)
                af[mt] = ldfrag(sA[cur], wr + mt * 16 + fr, cb);
            #pragma unroll
            for (int nt = 0; nt < 4; ++nt)
                bfm[nt] = ldfrag(sB[cur], wc + nt * 16 + fr, cb);
            #pragma unroll
            for (int mt = 0; mt < 2; ++mt)
                #pragma unroll
                for (int nt = 0; nt < 4; ++nt)
                    acc[mt][nt] = __builtin_amdgcn_mfma_f32_16x16x32_bf16(
                        af[mt], bfm[nt], acc[mt][nt], 0, 0, 0);
        }
        asm volatile("s_waitcnt lgkmcnt(0)" ::: "memory");
        __builtin_amdgcn_sched_barrier(0);
        __builtin_amdgcn_s_barrier();
    }

    #pragma unroll
    for (int mt = 0; mt < 2; ++mt)
        #pragma unroll
        for (int nt = 0; nt < 4; ++nt)
            #pragma unroll
            for (int r = 0; r < 4; ++r) {
                int gm = m0 + wr + mt * 16 + r4 + r;
                int gn = n0 + wc + nt * 16 + fr;
                Cout[(size_t)gm * DM + gn] = acc[mt][nt][r] + bo[gn];
            }
}

// ---------------- causal flash attention: 64 q-rows/wave, shared K/V --------
// Each wave owns BOTH 32-row granules of its rb (identical tile sequences):
// K staged once, V loaded once, consumed by granule a then granule b.
__device__ __forceinline__ void stageK64(const char* Kc, int t, char* myK, int lane) {
    const int krow8 = lane >> 3;
    const int kcol  = ((lane & 7) * 16) ^ (krow8 << 4);
    const char* kb = Kc + (size_t)t * 8192;
    #pragma unroll
    for (int i = 0; i < 8; ++i)
        gl16(kb + (i * 8 + krow8) * 128 + kcol, myK + i * 1024);
}

__global__ __launch_bounds__(256)
void attn_kernel(const unsigned short* __restrict__ Q,
                 const unsigned short* __restrict__ K,
                 const unsigned short* __restrict__ VT,
                 unsigned short* __restrict__ O)
{
    __shared__ char smem[4][8192];   // per-wave: K slice -> combine/epilogue buf

    const int bid = blockIdx.x;                  // 512
    const int xcd = bid & 7, idx = bid >> 3;     // idx 0..63
    const int bh  = xcd * 8 + (idx & 7);         // 8 bh per XCD (K/V L2-resident)
    const int blkgrp = idx >> 3;                 // 0..7
    const int tid = threadIdx.x, lane = tid & 63, wv = tid >> 6;
    const int rb  = 15 - (blkgrp * 2 + (wv >> 1));   // LPT: heavy rb first
    const int p   = wv & 1;
    const int q0  = rb * 64;
    const int ql = lane & 31, hi = lane >> 5;
    const int qga = q0 + ql;                     // granule a row
    const int qgb = q0 + 32 + ql;                // granule b row
    const int ndiag = rb;                        // same diagonal tile for a and b

    char* myK = smem[wv];

    const unsigned short* Qp = Q + (size_t)bh * SEQ * HD;
    const char* Kc  = (const char*)(K  + (size_t)bh * SEQ * HD);
    const char* Vfc = (const char*)(VT + (size_t)bh * SEQ * HD);  // fragment-linear

    bf16x8 qfa[4], qfb[4];
    #pragma unroll
    for (int s = 0; s < 4; ++s) {
        qfa[s] = __builtin_bit_cast(bf16x8,
            *(const s16x8*)(Qp + (size_t)qga * HD + s * 16 + hi * 8));
        qfb[s] = __builtin_bit_cast(bf16x8,
            *(const s16x8*)(Qp + (size_t)qgb * HD + s * 16 + hi * 8));
    }

    f32x16 o0a, o1a, o0b, o1b;
    #pragma unroll
    for (int i = 0; i < 16; ++i) { o0a[i] = 0.f; o1a[i] = 0.f; o0b[i] = 0.f; o1b[i] = 0.f; }
    float mra = -3.0e38f, lra = 0.f, mrb = -3.0e38f, lrb = 0.f;

    stageK64(Kc, p, myK, lane);      // p <= ndiag always (ndiag >= 1)

    for (int t = p; t <= ndiag; t += 2) {
        asm volatile("s_waitcnt vmcnt(0)" ::: "memory");   // K(t) in LDS
        __builtin_amdgcn_sched_barrier(0);

        // ---- granule a: QK^T
        f32x16 s0, s1;
        #pragma unroll
        for (int i = 0; i < 16; ++i) { s0[i] = 0.f; s1[i] = 0.f; }
        #pragma unroll
        for (int s = 0; s < 4; ++s) {
            const int cb = s * 32 + hi * 16;
            bf16x8 k0 = ldfrag(myK, ql, cb);
            bf16x8 k1 = ldfrag(myK, 32 + ql, cb);
            s0 = __builtin_amdgcn_mfma_f32_32x32x16_bf16(k0, qfa[s], s0, 0, 0, 0);
            s1 = __builtin_amdgcn_mfma_f32_32x32x16_bf16(k1, qfa[s], s1, 0, 0, 0);
        }
        asm volatile("s_waitcnt lgkmcnt(0)" ::: "memory");
        __builtin_amdgcn_sched_barrier(0);

        // V(t): 8 coalesced 1 KB loads, shared by both granules
        const char* vb = Vfc + (size_t)t * 8192;
        s16x8 vr[8];
        #pragma unroll
        for (int r = 0; r < 8; ++r)
            vr[r] = *(const s16x8*)(vb + r * 1024 + lane * 16);

        if (t == ndiag) {
            #pragma unroll
            for (int r = 0; r < 16; ++r) {
                const int kl = t * 64 + (r & 3) + 8 * (r >> 2) + 4 * hi;
                s0[r] = (kl      <= qga) ? s0[r] : -3.0e38f;
                s1[r] = (kl + 32 <= qga) ? s1[r] : -3.0e38f;
            }
        }

        // granule a softmax
        {
            float mt = s0[0];
            #pragma unroll
            for (int r = 1; r < 16; ++r) mt = fmaxf(mt, s0[r]);
            #pragma unroll
            for (int r = 0; r < 16; ++r) mt = fmaxf(mt, s1[r]);
            mt = fmaxf(mt, __shfl_xor(mt, 32, 64));
            if (!__all(mt - mra <= 8.0f)) {
                const float mnew = fmaxf(mra, mt);
                const float pc = __builtin_amdgcn_exp2f(mra - mnew);
                mra = mnew;
                lra *= pc;
                #pragma unroll
                for (int i = 0; i < 16; ++i) { o0a[i] *= pc; o1a[i] *= pc; }
            }
            float ts = 0.f;
            #pragma unroll
            for (int r = 0; r < 16; ++r) { s0[r] = __builtin_amdgcn_exp2f(s0[r] - mra); ts += s0[r]; }
            #pragma unroll
            for (int r = 0; r < 16; ++r) { s1[r] = __builtin_amdgcn_exp2f(s1[r] - mra); ts += s1[r]; }
            ts += __shfl_xor(ts, 32, 64);
            lra += ts;
        }

        // granule a PV
        #pragma unroll
        for (int s = 0; s < 4; ++s) {
            const f32x16 ps = (s < 2) ? s0 : s1;
            const int bse = (s & 1) * 8;
            unsigned w0 = pk2(ps[bse + 0], ps[bse + 1]);
            unsigned w1 = pk2(ps[bse + 2], ps[bse + 3]);
            unsigned w2 = pk2(ps[bse + 4], ps[bse + 5]);
            unsigned w3 = pk2(ps[bse + 6], ps[bse + 7]);
            unsigned x0 = (unsigned)__shfl_xor((int)(hi ? w0 : w2), 32, 64);
            unsigned x1 = (unsigned)__shfl_xor((int)(hi ? w1 : w3), 32, 64);
            u32x4 fw;
            fw[0] = hi ? x0 : w0;
            fw[1] = hi ? x1 : w1;
            fw[2] = hi ? w2 : x0;
            fw[3] = hi ? w3 : x1;
            const bf16x8 pfrag = __builtin_bit_cast(bf16x8, fw);
            o0a = __builtin_amdgcn_mfma_f32_32x32x16_bf16(
                __builtin_bit_cast(bf16x8, vr[2 * s]), pfrag, o0a, 0, 0, 0);
            o1a = __builtin_amdgcn_mfma_f32_32x32x16_bf16(
                __builtin_bit_cast(bf16x8, vr[2 * s + 1]), pfrag, o1a, 0, 0, 0);
        }

        // ---- granule b: QK^T (re-read K frags; overlaps a's PV)
        #pragma unroll
        for (int i = 0; i < 16; ++i) { s0[i] = 0.f; s1[i] = 0.f; }
        #pragma unroll
        for (int s = 0; s < 4; ++s) {
            const int cb = s * 32 + hi * 16;
            bf16x8 k0 = ldfrag(myK, ql, cb);
            bf16x8 k1 = ldfrag(myK, 32 + ql, cb);
            s0 = __builtin_amdgcn_mfma_f32_32x32x16_bf16(k0, qfb[s], s0, 0, 0, 0);
            s1 = __builtin_amdgcn_mfma_f32_32x32x16_bf16(k1, qfb[s], s1, 0, 0, 0);
        }
        asm volatile("s_waitcnt lgkmcnt(0)" ::: "memory");   // myK reads drained (WAR)
        __builtin_amdgcn_sched_barrier(0);

        // stage K(t+2): overlaps b's softmax+PV
        if (t + 2 <= ndiag) stageK64(Kc, t + 2, myK, lane);

        if (t == ndiag) {
            #pragma unroll
            for (int r = 0; r < 16; ++r) {
                const int kl = t * 64 + (r & 3) + 8 * (r >> 2) + 4 * hi;
                s0[r] = (kl      <= qgb) ? s0[r] : -3.0e38f;
                s1[r] = (kl + 32 <= qgb) ? s1[r] : -3.0e38f;
            }
        }

        // granule b softmax
        {
            float mt = s0[0];
            #pragma unroll
            for (int r = 1; r < 16; ++r) mt = fmaxf(mt, s0[r]);
            #pragma unroll
            for (int r = 0; r < 16; ++r) mt = fmaxf(mt, s1[r]);
            mt = fmaxf(mt, __shfl_xor(mt, 32, 64));
            if (!__all(mt - mrb <= 8.0f)) {
                const float mnew = fmaxf(mrb, mt);
                const float pc = __builtin_amdgcn_exp2f(mrb - mnew);
                mrb = mnew;
                lrb *= pc;
                #pragma unroll
                for (int i = 0; i < 16; ++i) { o0b[i] *= pc; o1b[i] *= pc; }
            }
            float ts = 0.f;
            #pragma unroll
            for (int r = 0; r < 16; ++r) { s0[r] = __builtin_amdgcn_exp2f(s0[r] - mrb); ts += s0[r]; }
            #pragma unroll
            for (int r = 0; r < 16; ++r) { s1[r] = __builtin_amdgcn_exp2f(s1[r] - mrb); ts += s1[r]; }
            ts += __shfl_xor(ts, 32, 64);
            lrb += ts;
        }

        // granule b PV
        #pragma unroll
        for (int s = 0; s < 4; ++s) {
            const f32x16 ps = (s < 2) ? s0 : s1;
            const int bse = (s & 1) * 8;
            unsigned w0 = pk2(ps[bse + 0], ps[bse + 1]);
            unsigned w1 = pk2(ps[bse + 2], ps[bse + 3]);
            unsigned w2 = pk2(ps[bse + 4], ps[bse + 5]);
            unsigned w3 = pk2(ps[bse + 6], ps[bse + 7]);
            unsigned x0 = (unsigned)__shfl_xor((int)(hi ? w0 : w2), 32, 64);
            unsigned x1 = (unsigned)__shfl_xor((int)(hi ? w1 : w3), 32, 64);
            u32x4 fw;
            fw[0] = hi ? x0 : w0;
            fw[1] = hi ? x1 : w1;
            fw[2] = hi ? w2 : x0;
            fw[3] = hi ? w3 : x1;
            const bf16x8 pfrag = __builtin_bit_cast(bf16x8, fw);
            o0b = __builtin_amdgcn_mfma_f32_32x32x16_bf16(
                __builtin_bit_cast(bf16x8, vr[2 * s]), pfrag, o0b, 0, 0, 0);
            o1b = __builtin_amdgcn_mfma_f32_32x32x16_bf16(
                __builtin_bit_cast(bf16x8, vr[2 * s + 1]), pfrag, o1b, 0, 0, 0);
        }
    }

    // ---------------- parity combine + epilogue (granule a, then b) ---------
    const int bb = bh >> 4, h = bh & 15;
    #pragma unroll
    for (int gsel = 0; gsel < 2; ++gsel) {
        const f32x16 po0 = gsel ? o0b : o0a;
        const f32x16 po1 = gsel ? o1b : o1a;
        const float  pm  = gsel ? mrb : mra;
        const float  pl  = gsel ? lrb : lra;
        const int    qrow0 = q0 + gsel * 32;

        if (p == 1) {
            unsigned* rec = (unsigned*)smem[wv] + lane * 21;
            #pragma unroll
            for (int i = 0; i < 8; ++i) rec[i]     = pk2(po0[2 * i], po0[2 * i + 1]);
            #pragma unroll
            for (int i = 0; i < 8; ++i) rec[8 + i] = pk2(po1[2 * i], po1[2 * i + 1]);
            rec[16] = __builtin_bit_cast(unsigned, pm);
            rec[17] = __builtin_bit_cast(unsigned, pl);
            asm volatile("s_waitcnt lgkmcnt(0)" ::: "memory");
        }
        __syncthreads();
        if (p == 0) {
            const unsigned* rec = (const unsigned*)smem[wv + 1] + lane * 21;
            const float m1 = __builtin_bit_cast(float, rec[16]);
            const float l1 = __builtin_bit_cast(float, rec[17]);
            const float ms = fmaxf(pm, m1);
            const float c0 = __builtin_amdgcn_exp2f(pm - ms);
            const float c1 = __builtin_amdgcn_exp2f(m1 - ms);
            const float inv = 1.0f / (pl * c0 + l1 * c1);
            const float a0 = c0 * inv, a1 = c1 * inv;

            unsigned short* sE = (unsigned short*)smem[wv];
            #pragma unroll
            for (int dt = 0; dt < 2; ++dt) {
                const f32x16 ov = dt ? po1 : po0;
                #pragma unroll
                for (int j = 0; j < 4; ++j) {
                    u16x4 w;
                    #pragma unroll
                    for (int i = 0; i < 4; ++i) {
                        const int ii = 4 * j + i;
                        const unsigned uw = rec[dt * 8 + (ii >> 1)];
                        const float pv = bf2f((unsigned short)((ii & 1) ? (uw >> 16) : (uw & 0xffff)));
                        w[i] = bfbits(ov[ii] * a0 + pv * a1);
                    }
                    *(u16x4*)&sE[ql * 72 + dt * 32 + 8 * j + 4 * hi] = w;
                }
            }
            asm volatile("s_waitcnt lgkmcnt(0)" ::: "memory");
            #pragma unroll
            for (int it = 0; it < 4; ++it) {
                const int ix = it * 64 + lane;
                const int qq = ix >> 3, c = ix & 7;
                s16x8 v = *(const s16x8*)&sE[qq * 72 + c * 8];
                *(s16x8*)(O + ((size_t)(bb * SEQ + qrow0 + qq) * DM + h * 64) + c * 8) = v;
            }
        }
        __syncthreads();   // a-phase fully consumed before b-phase overwrites
    }
}

extern "C" void kernel_launch(void* const* d_in, const int* in_sizes, int n_in,
                              void* d_out, int out_size, void* d_ws, size_t ws_size,
                              hipStream_t stream)
{
    const float* query = (const float*)d_in[0];
    const float* key   = (const float*)d_in[1];
    const float* value = (const float*)d_in[2];
    // d_in[3]: causal mask (tril) — hardcoded in attn_kernel
    const float* Wq = (const float*)d_in[4];
    const float* Wk = (const float*)d_in[5];
    const float* Wv = (const float*)d_in[6];
    const float* Wo = (const float*)d_in[7];
    const float* bo = (const float*)d_in[8];
    float* out = (float*)d_out;

    const size_t XE = (size_t)MTOT * DM;   // 4M elems
    const size_t WE = (size_t)DM * DM;     // 1M
    unsigned short* ws16 = (unsigned short*)d_ws;
    unsigned short* Xq16 = ws16;
    unsigned short* Xk16 = Xq16 + XE;
    unsigned short* Xv16 = Xk16 + XE;
    unsigned short* Wq16 = Xv16 + XE;
    unsigned short* Wk16 = Wq16 + WE;
    unsigned short* Wv16 = Wk16 + WE;
    unsigned short* Wo16 = Wv16 + WE;
    unsigned short* Qw   = Wo16 + WE;
    unsigned short* Kw   = Qw + XE;
    unsigned short* VTw  = Kw + XE;      // fragment-linear Vf
    unsigned short* AO   = VTw + XE;

    cvt_kernel<<<dim3(8192), dim3(256), 0, stream>>>(
        query, key, value, Wq, Wk, Wv, Wo,
        Xq16, Xk16, Xv16, Wq16, Wk16, Wv16, Wo16);

    proj_kernel<<<dim3(192), dim3(512), 0, stream>>>(
        Xq16, Xk16, Xv16, Wq16, Wk16, Wv16, Qw, Kw, VTw);

    attn_kernel<<<dim3(512), dim3(256), 0, stream>>>(Qw, Kw, VTw, AO);

    outproj_kernel<<<dim3(256), dim3(512), 0, stream>>>(AO, Wo16, bo, out);
}

// Round 17
// 89.718 us; speedup vs baseline: 1.0810x; 1.0810x over previous
//
#include <hip/hip_runtime.h>

typedef __bf16 bf16x8 __attribute__((ext_vector_type(8)));
typedef short  s16x8  __attribute__((ext_vector_type(8)));
typedef float  f32x4  __attribute__((ext_vector_type(4)));
typedef float  f32x16 __attribute__((ext_vector_type(16)));
typedef unsigned int   u32x4 __attribute__((ext_vector_type(4)));
typedef unsigned short u16x4 __attribute__((ext_vector_type(4)));

#define NH   16
#define HD   64
#define SEQ  1024
#define DM   1024
#define NB   4
#define MTOT 4096   // NB*SEQ

// 0.125 (1/sqrt(dk)) * log2(e): folded into Wq so QK^T scores are in log2 domain
#define SCALE_L2E 0.1803368801111204f

__device__ __forceinline__ unsigned short f2bf(float f) {
    unsigned u = __builtin_bit_cast(unsigned, f);
    u += 0x7FFFu + ((u >> 16) & 1u);          // round-to-nearest-even
    return (unsigned short)(u >> 16);
}

__device__ __forceinline__ s16x8 cvt8(f32x4 a, f32x4 b) {
    s16x8 r;
    r[0] = (short)f2bf(a[0]); r[1] = (short)f2bf(a[1]);
    r[2] = (short)f2bf(a[2]); r[3] = (short)f2bf(a[3]);
    r[4] = (short)f2bf(b[0]); r[5] = (short)f2bf(b[1]);
    r[6] = (short)f2bf(b[2]); r[7] = (short)f2bf(b[3]);
    return r;
}

__device__ __forceinline__ unsigned short bfbits(float x) {
    __bf16 h = (__bf16)x;
    return __builtin_bit_cast(unsigned short, h);
}
__device__ __forceinline__ float bf2f(unsigned short b) {
    unsigned u = (unsigned)b << 16;
    return __builtin_bit_cast(float, u);
}
__device__ __forceinline__ unsigned pk2(float a, float b) {
    return (unsigned)bfbits(a) | ((unsigned)bfbits(b) << 16);
}

__device__ __forceinline__ void gl16(const void* g, void* l) {
    __builtin_amdgcn_global_load_lds(
        (const __attribute__((address_space(1))) unsigned int*)g,
        (__attribute__((address_space(3))) unsigned int*)l, 16, 0, 0);
}

__device__ __forceinline__ bf16x8 ldfrag(const char* base, int row, int cb) {
    return __builtin_bit_cast(bf16x8,
        *(const s16x8*)(base + row * 128 + (cb ^ ((row & 7) << 4))));
}

// ---------------- fp32 -> bf16 convert pass (all 7 tensors) -----------------
__global__ __launch_bounds__(256)
void cvt_kernel(const float* __restrict__ q, const float* __restrict__ k,
                const float* __restrict__ v, const float* __restrict__ wq,
                const float* __restrict__ wk, const float* __restrict__ wv,
                const float* __restrict__ wo,
                unsigned short* __restrict__ dq, unsigned short* __restrict__ dk,
                unsigned short* __restrict__ dv, unsigned short* __restrict__ dwq,
                unsigned short* __restrict__ dwk, unsigned short* __restrict__ dwv,
                unsigned short* __restrict__ dwo)
{
    const int id = blockIdx.x;
    const float* s; unsigned short* d; int off; float scl = 1.0f;
    if (id < 6144) {                       // q,k,v: 2048 blocks each
        const int t = id >> 11; off = id & 2047;
        s = (t == 0) ? q : (t == 1) ? k : v;
        d = (t == 0) ? dq : (t == 1) ? dk : dv;
    } else {                               // weights: 512 blocks each
        const int w = (id - 6144) >> 9; off = (id - 6144) & 511;
        s = (w == 0) ? wq : (w == 1) ? wk : (w == 2) ? wv : wo;
        d = (w == 0) ? dwq : (w == 1) ? dwk : (w == 2) ? dwv : dwo;
        if (w == 0) scl = SCALE_L2E;
    }
    const int idx = off * 2048 + threadIdx.x * 8;
    const f32x4* sp = (const f32x4*)(s + idx);
    *(s16x8*)(d + idx) = cvt8(sp[0] * scl, sp[1] * scl);
}

// ---------------- staging helpers -------------------------------------------
// stage a 128-row x 64-col half-tile (16 KB) with 512 threads (2 gl16/thread)
__device__ __forceinline__ void stage_half(const unsigned short* __restrict__ src,
                                           int grow0, int k0, char* ldsdst, int tid)
{
    const int wv  = tid >> 6;                                // 0..7
    const int row = tid >> 3;                                // 0..63
    const int scx = ((tid & 7) * 16) ^ ((row & 7) << 4);
    gl16((const char*)(src + (size_t)(grow0 + row) * DM + k0) + scx,
         ldsdst + wv * 1024);
    gl16((const char*)(src + (size_t)(grow0 + 64 + row) * DM + k0) + scx,
         ldsdst + 8192 + wv * 1024);
}

// ---------------- QKV projection: 256x256 tile, 8-wave, 4-phase, gl16 -------
// V output layout is FRAGMENT-LINEAR: Vf[bh][t=s64-tile][r=(slot,dhalf)][lane]
__global__ __launch_bounds__(512, 2)
void proj_kernel(const unsigned short* __restrict__ Xq,
                 const unsigned short* __restrict__ Xk,
                 const unsigned short* __restrict__ Xv,
                 const unsigned short* __restrict__ Wq,
                 const unsigned short* __restrict__ Wk,
                 const unsigned short* __restrict__ Wv,
                 unsigned short* __restrict__ Qo, unsigned short* __restrict__ Ko,
                 unsigned short* __restrict__ VTo)
{
    __shared__ char smem[147456];

    const int bid = blockIdx.x;
    const int swz = (bid & 7) * 24 + (bid >> 3);
    const int which = swz >> 6;                 // 0..2
    const int rem   = swz & 63;
    const int m0 = (rem >> 2) * 256, n0 = (rem & 3) * 256;

    const unsigned short* X = (which == 0) ? Xq : (which == 1) ? Xk : Xv;
    const unsigned short* W = (which == 0) ? Wq : (which == 1) ? Wk : Wv;

    const int tid = threadIdx.x, lane = tid & 63, wv = tid >> 6;
    const int wrB = (wv >> 2) * 128;
    const int wcB = (wv & 3) * 64;
    const int fr = lane & 15, hi = lane >> 4, r4 = hi * 4;

    f32x4 acc[8][4];
    #pragma unroll
    for (int i = 0; i < 8; ++i)
        #pragma unroll
        for (int j = 0; j < 4; ++j) acc[i][j] = (f32x4){0.f, 0.f, 0.f, 0.f};

    stage_half(X, m0,       0, smem +     0, tid);
    stage_half(X, m0 + 128, 0, smem + 16384, tid);
    stage_half(W, n0,       0, smem + 32768, tid);
    stage_half(W, n0 + 128, 0, smem + 49152, tid);

    for (int t = 0; t < 16; ++t) {
        const char* Abuf = smem + (t & 1) * 65536;
        const char* Bbuf = Abuf + 32768;
        char* nb = smem + ((t & 1) ^ 1) * 65536;
        const int kn = (t + 1) * 64;

        bf16x8 af[2][4], bf01[2][2], bf23[2][2];

        // ---- phase 0: stage A-h0(t+1); counted vmcnt; barrier; af(qm0)+bf01; MFMA
        if (t < 15) {
            stage_half(X, m0, kn, nb, tid);
            asm volatile("s_waitcnt vmcnt(2)" ::: "memory");   // tile t fully landed
        } else {
            asm volatile("s_waitcnt vmcnt(0)" ::: "memory");
        }
        __builtin_amdgcn_s_barrier();
        __builtin_amdgcn_sched_barrier(0);
        #pragma unroll
        for (int ks = 0; ks < 2; ++ks) {
            const int cb = ks * 64 + hi * 16;
            #pragma unroll
            for (int mt = 0; mt < 4; ++mt) af[ks][mt] = ldfrag(Abuf, wrB + mt * 16 + fr, cb);
            #pragma unroll
            for (int nt = 0; nt < 2; ++nt) bf01[ks][nt] = ldfrag(Bbuf, wcB + nt * 16 + fr, cb);
        }
        __builtin_amdgcn_s_setprio(1);
        #pragma unroll
        for (int ks = 0; ks < 2; ++ks)
            #pragma unroll
            for (int mt = 0; mt < 4; ++mt)
                #pragma unroll
                for (int nt = 0; nt < 2; ++nt)
                    acc[mt][nt] = __builtin_amdgcn_mfma_f32_16x16x32_bf16(
                        af[ks][mt], bf01[ks][nt], acc[mt][nt], 0, 0, 0);
        __builtin_amdgcn_s_setprio(0);

        // ---- phase 1: bf23; stage A-h1(t+1); MFMA qm0 x nt{2,3}
        __builtin_amdgcn_s_barrier();
        __builtin_amdgcn_sched_barrier(0);
        #pragma unroll
        for (int ks = 0; ks < 2; ++ks) {
            const int cb = ks * 64 + hi * 16;
            #pragma unroll
            for (int nt = 0; nt < 2; ++nt) bf23[ks][nt] = ldfrag(Bbuf, wcB + 32 + nt * 16 + fr, cb);
        }
        if (t < 15) stage_half(X, m0 + 128, kn, nb + 16384, tid);
        __builtin_amdgcn_s_setprio(1);
        #pragma unroll
        for (int ks = 0; ks < 2; ++ks)
            #pragma unroll
            for (int mt = 0; mt < 4; ++mt)
                #pragma unroll
                for (int nt = 0; nt < 2; ++nt)
                    acc[mt][nt + 2] = __builtin_amdgcn_mfma_f32_16x16x32_bf16(
                        af[ks][mt], bf23[ks][nt], acc[mt][nt + 2], 0, 0, 0);
        __builtin_amdgcn_s_setprio(0);

        // ---- phase 2: af(qm1); stage B-h0(t+1); MFMA qm1 x nt{0,1}
        __builtin_amdgcn_s_barrier();
        __builtin_amdgcn_sched_barrier(0);
        #pragma unroll
        for (int ks = 0; ks < 2; ++ks) {
            const int cb = ks * 64 + hi * 16;
            #pragma unroll
            for (int mt = 0; mt < 4; ++mt) af[ks][mt] = ldfrag(Abuf, wrB + 64 + mt * 16 + fr, cb);
        }
        if (t < 15) stage_half(W, n0, kn, nb + 32768, tid);
        __builtin_amdgcn_s_setprio(1);
        #pragma unroll
        for (int ks = 0; ks < 2; ++ks)
            #pragma unroll
            for (int mt = 0; mt < 4; ++mt)
                #pragma unroll
                for (int nt = 0; nt < 2; ++nt)
                    acc[mt + 4][nt] = __builtin_amdgcn_mfma_f32_16x16x32_bf16(
                        af[ks][mt], bf01[ks][nt], acc[mt + 4][nt], 0, 0, 0);
        __builtin_amdgcn_s_setprio(0);

        // ---- phase 3: stage B-h1(t+1); MFMA qm1 x nt{2,3}
        __builtin_amdgcn_s_barrier();
        __builtin_amdgcn_sched_barrier(0);
        if (t < 15) stage_half(W, n0 + 128, kn, nb + 49152, tid);
        __builtin_amdgcn_s_setprio(1);
        #pragma unroll
        for (int ks = 0; ks < 2; ++ks)
            #pragma unroll
            for (int mt = 0; mt < 4; ++mt)
                #pragma unroll
                for (int nt = 0; nt < 2; ++nt)
                    acc[mt + 4][nt + 2] = __builtin_amdgcn_mfma_f32_16x16x32_bf16(
                        af[ks][mt], bf23[ks][nt], acc[mt + 4][nt + 2], 0, 0, 0);
        __builtin_amdgcn_s_setprio(0);
    }

    // ---------------- vectorized epilogue via per-wave LDS bounce -----------
    __syncthreads();

    unsigned short* sE = (unsigned short*)(smem + wv * 18432);
    #pragma unroll
    for (int mt = 0; mt < 8; ++mt)
        #pragma unroll
        for (int nt = 0; nt < 4; ++nt)
            #pragma unroll
            for (int r = 0; r < 4; ++r) {
                const int row = mt * 16 + r4 + r;
                const int col = nt * 16 + fr;
                sE[row * 72 + (col ^ (((row >> 3) & 7) << 3))] = f2bf(acc[mt][nt][r]);
            }
    asm volatile("s_waitcnt lgkmcnt(0)" ::: "memory");

    const int hB    = (n0 + wcB) >> 6;
    const int sbase = m0 + wrB;
    const int bb    = sbase >> 10;
    const int srow0 = sbase & 1023;

    if (which < 2) {
        unsigned short* QK = ((which == 0) ? Qo : Ko)
            + (((size_t)(bb * NH + hB)) * SEQ + srow0) * HD;
        #pragma unroll
        for (int it = 0; it < 16; ++it) {
            const int idx = it * 64 + lane;
            const int row = idx >> 3, c = idx & 7;
            s16x8 v = *(const s16x8*)&sE[row * 72 + ((c ^ ((row >> 3) & 7)) * 8)];
            *(s16x8*)(QK + (size_t)row * HD + c * 8) = v;
        }
    } else {
        const int t0 = srow0 >> 6;                       // 2 tiles owned
        unsigned short* VD = VTo + (size_t)(bb * NH + hB) * (SEQ * HD)
                                 + (size_t)t0 * 4096;
        #pragma unroll
        for (int it = 0; it < 16; ++it) {
            const int tt = it >> 3, r = it & 7;
            const int sb = tt * 64 + (r >> 1) * 16 + (lane >> 5) * 8;
            const int d  = (lane & 31) + (r & 1) * 32;
            s16x8 v;
            #pragma unroll
            for (int j = 0; j < 8; ++j) {
                const int row = sb + j;
                v[j] = (short)sE[row * 72 + (d ^ (((row >> 3) & 7) << 3))];
            }
            *(s16x8*)(VD + (size_t)(tt * 8 + r) * 512 + lane * 8) = v;  // 1 KB contig
        }
    }
}

// ---------------- output projection: 128^2, 8 waves (2/SIMD), 2-phase -------
__global__ __launch_bounds__(512, 2)
void outproj_kernel(const unsigned short* __restrict__ A,
                    const unsigned short* __restrict__ Wo,
                    const float* __restrict__ bo,
                    float* __restrict__ Cout)
{
    const int bid = blockIdx.x;
    const int swz = (bid & 7) * 32 + (bid >> 3);     // 256 blocks
    const int m0 = (swz >> 3) * 128, n0 = (swz & 7) * 128;

    __shared__ char sA[2][16384];
    __shared__ char sB[2][16384];

    const int tid = threadIdx.x, lane = tid & 63, wv = tid >> 6;
    const int wr = (wv >> 1) * 32;       // 4 M-groups of 32 rows
    const int wc = (wv & 1) * 64;        // 2 N-groups of 64 cols
    const int fr = lane & 15, hi = lane >> 4, r4 = hi * 4;

    f32x4 acc[2][4];
    #pragma unroll
    for (int i = 0; i < 2; ++i)
        #pragma unroll
        for (int j = 0; j < 4; ++j) acc[i][j] = (f32x4){0.f, 0.f, 0.f, 0.f};

    stage_half(A,  m0, 0, sA[0], tid);
    stage_half(Wo, n0, 0, sB[0], tid);

    for (int kt = 0; kt < 16; ++kt) {
        const int cur = kt & 1;
        if (kt < 15) {
            stage_half(A,  m0, (kt + 1) * 64, sA[cur ^ 1], tid);
            stage_half(Wo, n0, (kt + 1) * 64, sB[cur ^ 1], tid);
            asm volatile("s_waitcnt vmcnt(4)" ::: "memory");   // tile kt landed
        } else {
            asm volatile("s_waitcnt vmcnt(0)" ::: "memory");
        }
        __builtin_amdgcn_s_barrier();
        __builtin_amdgcn_sched_barrier(0);
        #pragma unroll
        for (int ks = 0; ks < 2; ++ks) {
            const int cb = ks * 64 + hi * 16;
            bf16x8 af[2], bfm[4];
            #pragma unroll
            for (int mt = 0; mt < 2; ++mt)
                af[mt] = ldfrag(sA[cur], wr + mt * 16 + fr, cb);
            #pragma unroll
            for (int nt = 0; nt < 4; ++nt)
                bfm[nt] = ldfrag(sB[cur], wc + nt * 16 + fr, cb);
            #pragma unroll
            for (int mt = 0; mt < 2; ++mt)
                #pragma unroll
                for (int nt = 0; nt < 4; ++nt)
                    acc[mt][nt] = __builtin_amdgcn_mfma_f32_16x16x32_bf16(
                        af[mt], bfm[nt], acc[mt][nt], 0, 0, 0);
        }
        asm volatile("s_waitcnt lgkmcnt(0)" ::: "memory");
        __builtin_amdgcn_sched_barrier(0);
        __builtin_amdgcn_s_barrier();
    }

    #pragma unroll
    for (int mt = 0; mt < 2; ++mt)
        #pragma unroll
        for (int nt = 0; nt < 4; ++nt)
            #pragma unroll
            for (int r = 0; r < 4; ++r) {
                int gm = m0 + wr + mt * 16 + r4 + r;
                int gn = n0 + wc + nt * 16 + fr;
                Cout[(size_t)gm * DM + gn] = acc[mt][nt][r] + bo[gn];
            }
}

// ---------------- causal flash attention: barrier-free, KV-parity split -----
// (R9 structure: V after QK^T, no setprio)
__device__ __forceinline__ void stageK64(const char* Kc, int t, char* myK, int lane) {
    const int krow8 = lane >> 3;
    const int kcol  = ((lane & 7) * 16) ^ (krow8 << 4);
    const char* kb = Kc + (size_t)t * 8192;
    #pragma unroll
    for (int i = 0; i < 8; ++i)
        gl16(kb + (i * 8 + krow8) * 128 + kcol, myK + i * 1024);
}

__global__ __launch_bounds__(256)
void attn_kernel(const unsigned short* __restrict__ Q,
                 const unsigned short* __restrict__ K,
                 const unsigned short* __restrict__ VT,
                 unsigned short* __restrict__ O)
{
    __shared__ char smem[4][8192];   // per-wave: K slice -> combine/epilogue buf

    const int bid = blockIdx.x;                  // 1024
    const int xcd = bid & 7, idx = bid >> 3;     // idx 0..127
    const int bh  = xcd * 8 + (idx & 7);         // 8 bh per XCD (K/V L2-resident)
    const int rb  = 15 - (idx >> 3);             // row-block 0..15, LPT
    const int tid = threadIdx.x, lane = tid & 63, wv = tid >> 6;
    const int g = wv >> 1, p = wv & 1;
    const int q0w = rb * 64 + g * 32;            // this wave's 32 q-rows
    const int ql = lane & 31, hi = lane >> 5;
    const int qg = q0w + ql;
    const int ndiag = q0w >> 6;                  // diagonal 64-k tile

    char* myK = smem[wv];

    const unsigned short* Qp = Q + (size_t)bh * SEQ * HD;
    const char* Kc  = (const char*)(K  + (size_t)bh * SEQ * HD);
    const char* Vfc = (const char*)(VT + (size_t)bh * SEQ * HD);  // fragment-linear

    bf16x8 qf[4];
    #pragma unroll
    for (int s = 0; s < 4; ++s)
        qf[s] = __builtin_bit_cast(bf16x8,
            *(const s16x8*)(Qp + (size_t)qg * HD + s * 16 + hi * 8));

    f32x16 o0, o1;
    #pragma unroll
    for (int i = 0; i < 16; ++i) { o0[i] = 0.f; o1[i] = 0.f; }
    float mrow = -3.0e38f, lrow = 0.f;

    if (p <= ndiag) stageK64(Kc, p, myK, lane);

    for (int t = p; t <= ndiag; t += 2) {
        asm volatile("s_waitcnt vmcnt(0)" ::: "memory");   // K(t) in LDS
        __builtin_amdgcn_sched_barrier(0);

        // QK^T: s0 = S[k=0..31][q], s1 = S[k=32..63][q]
        f32x16 s0, s1;
        #pragma unroll
        for (int i = 0; i < 16; ++i) { s0[i] = 0.f; s1[i] = 0.f; }
        #pragma unroll
        for (int s = 0; s < 4; ++s) {
            const int cb = s * 32 + hi * 16;
            bf16x8 k0 = ldfrag(myK, ql, cb);
            bf16x8 k1 = ldfrag(myK, 32 + ql, cb);
            s0 = __builtin_amdgcn_mfma_f32_32x32x16_bf16(k0, qf[s], s0, 0, 0, 0);
            s1 = __builtin_amdgcn_mfma_f32_32x32x16_bf16(k1, qf[s], s1, 0, 0, 0);
        }
        asm volatile("s_waitcnt lgkmcnt(0)" ::: "memory"); // ds_read data landed
        __builtin_amdgcn_sched_barrier(0);

        // V(t) from fragment-linear layout: 8 coalesced 1 KB loads
        const char* vb = Vfc + (size_t)t * 8192;
        s16x8 vr[8];
        #pragma unroll
        for (int r = 0; r < 8; ++r)
            vr[r] = *(const s16x8*)(vb + r * 1024 + lane * 16);
        // stage K(t+2): overlaps softmax + PV (same-wave vmcnt ordering)
        if (t + 2 <= ndiag) stageK64(Kc, t + 2, myK, lane);

        if (t == ndiag) {                 // causal mask, diagonal tile only
            #pragma unroll
            for (int r = 0; r < 16; ++r) {
                const int kl = t * 64 + (r & 3) + 8 * (r >> 2) + 4 * hi;
                s0[r] = (kl      <= qg) ? s0[r] : -3.0e38f;
                s1[r] = (kl + 32 <= qg) ? s1[r] : -3.0e38f;
            }
        }

        // row max (lane-local tree + pair swap)
        float mt = s0[0];
        #pragma unroll
        for (int r = 1; r < 16; ++r) mt = fmaxf(mt, s0[r]);
        #pragma unroll
        for (int r = 0; r < 16; ++r) mt = fmaxf(mt, s1[r]);
        mt = fmaxf(mt, __shfl_xor(mt, 32, 64));

        // T13 defer-max: skip rescale while tile max stays within 8 (log2)
        if (!__all(mt - mrow <= 8.0f)) {
            const float mnew = fmaxf(mrow, mt);
            const float pc = __builtin_amdgcn_exp2f(mrow - mnew);
            mrow = mnew;
            lrow *= pc;
            #pragma unroll
            for (int i = 0; i < 16; ++i) { o0[i] *= pc; o1[i] *= pc; }
        }

        float ts = 0.f;
        #pragma unroll
        for (int r = 0; r < 16; ++r) { s0[r] = __builtin_amdgcn_exp2f(s0[r] - mrow); ts += s0[r]; }
        #pragma unroll
        for (int r = 0; r < 16; ++r) { s1[r] = __builtin_amdgcn_exp2f(s1[r] - mrow); ts += s1[r]; }
        ts += __shfl_xor(ts, 32, 64);
        lrow += ts;

        // P -> bf16 B-fragments (T12 exchange) + PV from V regs
        #pragma unroll
        for (int s = 0; s < 4; ++s) {
            const f32x16 ps = (s < 2) ? s0 : s1;
            const int bse = (s & 1) * 8;
            unsigned w0 = pk2(ps[bse + 0], ps[bse + 1]);
            unsigned w1 = pk2(ps[bse + 2], ps[bse + 3]);
            unsigned w2 = pk2(ps[bse + 4], ps[bse + 5]);
            unsigned w3 = pk2(ps[bse + 6], ps[bse + 7]);
            unsigned x0 = (unsigned)__shfl_xor((int)(hi ? w0 : w2), 32, 64);
            unsigned x1 = (unsigned)__shfl_xor((int)(hi ? w1 : w3), 32, 64);
            u32x4 fw;
            fw[0] = hi ? x0 : w0;
            fw[1] = hi ? x1 : w1;
            fw[2] = hi ? w2 : x0;
            fw[3] = hi ? w3 : x1;
            const bf16x8 pfrag = __builtin_bit_cast(bf16x8, fw);
            o0 = __builtin_amdgcn_mfma_f32_32x32x16_bf16(
                __builtin_bit_cast(bf16x8, vr[2 * s]), pfrag, o0, 0, 0, 0);
            o1 = __builtin_amdgcn_mfma_f32_32x32x16_bf16(
                __builtin_bit_cast(bf16x8, vr[2 * s + 1]), pfrag, o1, 0, 0, 0);
        }
    }

    // ---------------- parity combine (one barrier) + epilogue ---------------
    if (p == 1) {
        unsigned* rec = (unsigned*)smem[wv] + lane * 21;
        #pragma unroll
        for (int i = 0; i < 8; ++i) rec[i]     = pk2(o0[2 * i], o0[2 * i + 1]);
        #pragma unroll
        for (int i = 0; i < 8; ++i) rec[8 + i] = pk2(o1[2 * i], o1[2 * i + 1]);
        rec[16] = __builtin_bit_cast(unsigned, mrow);
        rec[17] = __builtin_bit_cast(unsigned, lrow);
        asm volatile("s_waitcnt lgkmcnt(0)" ::: "memory");
    }
    __syncthreads();
    if (p == 0) {
        const unsigned* rec = (const unsigned*)smem[wv + 1] + lane * 21;
        const float m1 = __builtin_bit_cast(float, rec[16]);
        const float l1 = __builtin_bit_cast(float, rec[17]);
        const float ms = fmaxf(mrow, m1);
        const float c0 = __builtin_amdgcn_exp2f(mrow - ms);
        const float c1 = __builtin_amdgcn_exp2f(m1 - ms);
        const float inv = 1.0f / (lrow * c0 + l1 * c1);
        const float a0 = c0 * inv, a1 = c1 * inv;

        unsigned short* sE = (unsigned short*)smem[wv];
        #pragma unroll
        for (int dt = 0; dt < 2; ++dt) {
            const f32x16 ov = dt ? o1 : o0;
            #pragma unroll
            for (int j = 0; j < 4; ++j) {
                u16x4 w;
                #pragma unroll
                for (int i = 0; i < 4; ++i) {
                    const int ii = 4 * j + i;
                    const unsigned uw = rec[dt * 8 + (ii >> 1)];
                    const float pv = bf2f((unsigned short)((ii & 1) ? (uw >> 16) : (uw & 0xffff)));
                    w[i] = bfbits(ov[ii] * a0 + pv * a1);
                }
                *(u16x4*)&sE[ql * 72 + dt * 32 + 8 * j + 4 * hi] = w;
            }
        }
        asm volatile("s_waitcnt lgkmcnt(0)" ::: "memory");
        const int bb = bh >> 4, h = bh & 15;
        #pragma unroll
        for (int it = 0; it < 4; ++it) {
            const int ix = it * 64 + lane;
            const int qq = ix >> 3, c = ix & 7;
            s16x8 v = *(const s16x8*)&sE[qq * 72 + c * 8];
            *(s16x8*)(O + ((size_t)(bb * SEQ + q0w + qq) * DM + h * 64) + c * 8) = v;
        }
    }
}

extern "C" void kernel_launch(void* const* d_in, const int* in_sizes, int n_in,
                              void* d_out, int out_size, void* d_ws, size_t ws_size,
                              hipStream_t stream)
{
    const float* query = (const float*)d_in[0];
    const float* key   = (const float*)d_in[1];
    const float* value = (const float*)d_in[2];
    // d_in[3]: causal mask (tril) — hardcoded in attn_kernel
    const float* Wq = (const float*)d_in[4];
    const float* Wk = (const float*)d_in[5];
    const float* Wv = (const float*)d_in[6];
    const float* Wo = (const float*)d_in[7];
    const float* bo = (const float*)d_in[8];
    float* out = (float*)d_out;

    const size_t XE = (size_t)MTOT * DM;   // 4M elems
    const size_t WE = (size_t)DM * DM;     // 1M
    unsigned short* ws16 = (unsigned short*)d_ws;
    unsigned short* Xq16 = ws16;
    unsigned short* Xk16 = Xq16 + XE;
    unsigned short* Xv16 = Xk16 + XE;
    unsigned short* Wq16 = Xv16 + XE;
    unsigned short* Wk16 = Wq16 + WE;
    unsigned short* Wv16 = Wk16 + WE;
    unsigned short* Wo16 = Wv16 + WE;
    unsigned short* Qw   = Wo16 + WE;
    unsigned short* Kw   = Qw + XE;
    unsigned short* VTw  = Kw + XE;      // fragment-linear Vf
    unsigned short* AO   = VTw + XE;

    cvt_kernel<<<dim3(8192), dim3(256), 0, stream>>>(
        query, key, value, Wq, Wk, Wv, Wo,
        Xq16, Xk16, Xv16, Wq16, Wk16, Wv16, Wo16);

    proj_kernel<<<dim3(192), dim3(512), 0, stream>>>(
        Xq16, Xk16, Xv16, Wq16, Wk16, Wv16, Qw, Kw, VTw);

    attn_kernel<<<dim3(1024), dim3(256), 0, stream>>>(Qw, Kw, VTw, AO);

    outproj_kernel<<<dim3(256), dim3(512), 0, stream>>>(AO, Wo16, bo, out);
}